// Round 6
// baseline (51.272 us; speedup 1.0000x reference)
//
#include <hip/hip_runtime.h>

// G=14, B=64, T=2048, H=6
#define Gc 14
#define Hc 6
#define NPc (64*2048)          // B*T points
#define LOG_2PI 1.8378770664093453f

typedef float v2f __attribute__((ext_vector_type(2)));

__device__ __forceinline__ float frsq(float x){ return __builtin_amdgcn_rsqf(x); }

// DPP quad_perm broadcast within lane pairs (1-cycle VALU, no LDS):
//   0xA0 = quad_perm [0,0,2,2] -> pair gets EVEN lane's value
//   0xF5 = quad_perm [1,1,3,3] -> pair gets ODD lane's value
template<int CTRL>
__device__ __forceinline__ float dppf(float x){
    union { float f; int i; } u; u.f = x;
    u.i = __builtin_amdgcn_update_dpp(0, u.i, CTRL, 0xF, 0xF, true);
    return u.f;
}
template<int OQ>
__device__ __forceinline__ float bcast(float x){
    return (OQ == 0) ? dppf<0xA0>(x) : dppf<0xF5>(x);
}

// One sweep of N-1 chained gprods.
// Head channel = component C of v2f J on owner lane OQ (cur on lane0 / nxt on lane1).
// Identities (|r*C|==1): x3 = a1*x1 - a2*x2 ; x4 = s2*x1 + s1*x2, with
//   S = rsqrt(C1^2+C2^2), s1 = C2*S, s2 = C1*S, a1 = copysign(s1,C1), a2 = copysign(s2,C2).
// logC == 0 exactly -> dropped. Head channel gets x4 = sqrt(C1^2+C2^2) = 1/std4. OK.
// Lane0's st = cur channels, lane1's st = nxt channels: one uniform packed update
// stream serves both arrays. b is duplicated & identical on both lanes.
template<int J, int C, int N, int OQ>
__device__ __forceinline__ void sweep(v2f (&st)[Gc][3], float (&bb)[Gc]){
#pragma unroll
    for (int i = 0; i < N - 1; ++i){
        const float C1 = bcast<OQ>(st[i][J][C]);
        const float C2 = bcast<OQ>(st[i + 1][J][C]);
        const float S  = frsq(fmaf(C1, C1, C2 * C2));   // 1 transcendental per gprod
        const float s1 = C2 * S, s2 = C1 * S;
        const float a1 = copysignf(s1, C1), a2 = copysignf(s2, C2);
        const v2f A1 = {a1, a1}, A2 = {a2, a2}, S1 = {s1, s1}, S2 = {s2, s2};
        // 3 packed channel-pair updates: 12 v_pk ops cover 6 channels x (cur|nxt)
#pragma unroll
        for (int j = 0; j < 3; ++j){
            const v2f x = st[i][j], y = st[i + 1][j];
            const v2f t = y * A2, u = y * S1;
            st[i][j]     = __builtin_elementwise_fma(x, A1, -t);
            st[i + 1][j] = __builtin_elementwise_fma(x, S2, u);
        }
        // bias channel (scalar; bit-identical on both lanes)
        {
            const float x = bb[i], y = bb[i + 1];
            bb[i]     = fmaf(x, a1, -(y * a2));
            bb[i + 1] = fmaf(x, s2, y * s1);
        }
    }
}

__global__ void __launch_bounds__(256, 4)   // 256-thr block, 4 waves/EU -> 128-VGPR cap
gaussmerge_kernel(const float* __restrict__ cur_in,
                  const float* __restrict__ nxt_in,
                  const float* __restrict__ b_in,
                  float* __restrict__ out)
{
    const int tid = threadIdx.x;
    const int q = tid & 1;                          // 0: cur-owner, 1: nxt-owner
    const int p = blockIdx.x * 128 + (tid >> 1);    // point index

    v2f   st[Gc][3];
    float bb[Gc];

    const float* abase = (q ? nxt_in : cur_in) + (size_t)p * Hc;
    const float* bp    = b_in + p;
#pragma unroll
    for (int g = 0; g < Gc; ++g){
        const v2f* a = (const v2f*)(abase + (size_t)g * (NPc * Hc));
        st[g][0] = a[0]; st[g][1] = a[1]; st[g][2] = a[2];
        bb[g] = bp[(size_t)g * NPc];
    }

    float LC = 0.0f;   // valid on lane0 only (log args are garbage on lane1, unused)

    // ---- phase 1: head = cur[k] (lane0); k -> (J=k>>1, C=k&1); n = 14-k ----
    sweep<0, 0, 14, 0>(st, bb); LC -= __logf(fabsf(st[13][0][0]));
    sweep<0, 1, 13, 0>(st, bb); LC -= __logf(fabsf(st[12][0][1]));
    sweep<1, 0, 12, 0>(st, bb); LC -= __logf(fabsf(st[11][1][0]));
    sweep<1, 1, 11, 0>(st, bb); LC -= __logf(fabsf(st[10][1][1]));
    sweep<2, 0, 10, 0>(st, bb); LC -= __logf(fabsf(st[ 9][2][0]));
    sweep<2, 1,  9, 0>(st, bb); LC -= __logf(fabsf(st[ 8][2][1]));

    // ---- phase 2: head = nxt[k] (lane1); n = 8-k; popped slot m = 7-k ----
    float* outN = out;                               // (6, B, T, H)
    float* outB = out + (size_t)Hc * NPc * Hc;       // (6, B, T)
    float* outL = outB + (size_t)Hc * NPc;           // (B, T)

#define PH2(K, J, C, N)                                                         \
    sweep<J, C, N, 1>(st, bb);                                                  \
    {                                                                           \
        constexpr int m = 7 - (K);                                              \
        if (q) {                                                                \
            v2f* o = (v2f*)(outN + (size_t)(K) * (NPc * Hc) + (size_t)p * Hc);  \
            o[0] = st[m][0]; o[1] = st[m][1]; o[2] = st[m][2];                  \
        } else {                                                                \
            outB[(size_t)(K) * NPc + p] = bb[m];                                \
        }                                                                       \
    }

    PH2(0, 0, 0, 8)
    PH2(1, 0, 1, 7)
    PH2(2, 1, 0, 6)
    PH2(3, 1, 1, 5)
    PH2(4, 2, 0, 4)
    PH2(5, 2, 1, 3)
#undef PH2

    // ---- epilogue: remaining biases (slots 0,1; identical on both lanes) ----
    LC += -0.5f * (LOG_2PI + bb[0] * bb[0]);
    LC += -0.5f * (LOG_2PI + bb[1] * bb[1]);
    if (q == 0) outL[p] = LC;
}

extern "C" void kernel_launch(void* const* d_in, const int* in_sizes, int n_in,
                              void* d_out, int out_size, void* d_ws, size_t ws_size,
                              hipStream_t stream) {
    const float* cur = (const float*)d_in[0];
    const float* nxt = (const float*)d_in[1];
    const float* bia = (const float*)d_in[2];
    float* out = (float*)d_out;

    // 2 threads per point: 256-thread blocks cover 128 points each.
    dim3 grid((NPc * 2) / 256), block(256);
    gaussmerge_kernel<<<grid, block, 0, stream>>>(cur, nxt, bia, out);
}

// Round 7
// 31.245 us; speedup vs baseline: 1.6410x; 1.6410x over previous
//
#include <hip/hip_runtime.h>

// G=14, B=64, T=2048, H=6
#define Gc 14
#define Hc 6
#define NPc (64*2048)          // B*T points
#define LOG_2PI 1.8378770664093453f

typedef float v2f __attribute__((ext_vector_type(2)));

__device__ __forceinline__ float frsq(float x){ return __builtin_amdgcn_rsqf(x); }

// DPP quad_perm broadcast within lane pairs (1-cycle VALU, no LDS):
//   0xA0 = quad_perm [0,0,2,2] -> pair gets EVEN lane's value
//   0xF5 = quad_perm [1,1,3,3] -> pair gets ODD lane's value
template<int CTRL>
__device__ __forceinline__ float dppf(float x){
    union { float f; int i; } u; u.f = x;
    u.i = __builtin_amdgcn_update_dpp(0, u.i, CTRL, 0xF, 0xF, true);
    return u.f;
}
template<int OQ>
__device__ __forceinline__ float bcast(float x){
    return (OQ == 0) ? dppf<0xA0>(x) : dppf<0xF5>(x);
}

// One sweep of N-1 chained gprods.
// Head channel = component C of v2f J on owner lane OQ (cur on lane0 / nxt on lane1).
// Identities (|r*C|==1): x3 = a1*x1 - a2*x2 ; x4 = s2*x1 + s1*x2, with
//   S = rsqrt(C1^2+C2^2), s1 = C2*S, s2 = C1*S, a1 = copysign(s1,C1), a2 = copysign(s2,C2).
// logC == 0 exactly -> dropped. Head channel gets x4 = sqrt(C1^2+C2^2) = 1/std4. OK.
// Lane0's st = cur channels, lane1's st = nxt channels: one uniform packed update
// stream serves both arrays. b is duplicated & bit-identical on both lanes.
template<int J, int C, int N, int OQ>
__device__ __forceinline__ void sweep(v2f (&st)[Gc][3], float (&bb)[Gc]){
#pragma unroll
    for (int i = 0; i < N - 1; ++i){
        const float C1 = bcast<OQ>(st[i][J][C]);
        const float C2 = bcast<OQ>(st[i + 1][J][C]);
        const float S  = frsq(fmaf(C1, C1, C2 * C2));   // 1 transcendental per gprod
        const float s1 = C2 * S, s2 = C1 * S;
        const float a1 = copysignf(s1, C1), a2 = copysignf(s2, C2);
        const v2f A1 = {a1, a1}, A2 = {a2, a2}, S1 = {s1, s1}, S2 = {s2, s2};
        // 3 packed channel-pair updates: 12 v_pk ops cover 6 channels x (cur|nxt)
#pragma unroll
        for (int j = 0; j < 3; ++j){
            const v2f x = st[i][j], y = st[i + 1][j];
            const v2f t = y * A2, u = y * S1;
            st[i][j]     = __builtin_elementwise_fma(x, A1, -t);
            st[i + 1][j] = __builtin_elementwise_fma(x, S2, u);
        }
        // bias channel (scalar; bit-identical on both lanes)
        {
            const float x = bb[i], y = bb[i + 1];
            bb[i]     = fmaf(x, a1, -(y * a2));
            bb[i + 1] = fmaf(x, s2, y * s1);
        }
    }
}

// NOTE: on this toolchain __launch_bounds__(256, N) caps VGPRs at ~256/N
// (empirical: N=4 -> 64-VGPR cap -> spill storm in rounds 4 & 6).
// N=2 -> 128-VGPR cap == the 4-waves/SIMD occupancy tier, matching the
// grid's 4096 waves (4/SIMD fully resident). State needs ~120 regs.
__global__ void __launch_bounds__(256, 2)
gaussmerge_kernel(const float* __restrict__ cur_in,
                  const float* __restrict__ nxt_in,
                  const float* __restrict__ b_in,
                  float* __restrict__ out)
{
    const int tid = threadIdx.x;
    const int q = tid & 1;                          // 0: cur-owner, 1: nxt-owner
    const int p = blockIdx.x * 128 + (tid >> 1);    // point index

    v2f   st[Gc][3];
    float bb[Gc];

    const float* abase = (q ? nxt_in : cur_in) + (size_t)p * Hc;
    const float* bp    = b_in + p;
#pragma unroll
    for (int g = 0; g < Gc; ++g){
        const v2f* a = (const v2f*)(abase + (size_t)g * (NPc * Hc));
        st[g][0] = a[0]; st[g][1] = a[1]; st[g][2] = a[2];
        bb[g] = bp[(size_t)g * NPc];
    }

    float LC = 0.0f;   // valid on lane0 only (log args are garbage on lane1, unused)

    // ---- phase 1: head = cur[k] (lane0); k -> (J=k>>1, C=k&1); n = 14-k ----
    sweep<0, 0, 14, 0>(st, bb); LC -= __logf(fabsf(st[13][0][0]));
    sweep<0, 1, 13, 0>(st, bb); LC -= __logf(fabsf(st[12][0][1]));
    sweep<1, 0, 12, 0>(st, bb); LC -= __logf(fabsf(st[11][1][0]));
    sweep<1, 1, 11, 0>(st, bb); LC -= __logf(fabsf(st[10][1][1]));
    sweep<2, 0, 10, 0>(st, bb); LC -= __logf(fabsf(st[ 9][2][0]));
    sweep<2, 1,  9, 0>(st, bb); LC -= __logf(fabsf(st[ 8][2][1]));

    // ---- phase 2: head = nxt[k] (lane1); n = 8-k; popped slot m = 7-k ----
    float* outN = out;                               // (6, B, T, H)
    float* outB = out + (size_t)Hc * NPc * Hc;       // (6, B, T)
    float* outL = outB + (size_t)Hc * NPc;           // (B, T)

#define PH2(K, J, C, N)                                                         \
    sweep<J, C, N, 1>(st, bb);                                                  \
    {                                                                           \
        constexpr int m = 7 - (K);                                              \
        if (q) {                                                                \
            v2f* o = (v2f*)(outN + (size_t)(K) * (NPc * Hc) + (size_t)p * Hc);  \
            o[0] = st[m][0]; o[1] = st[m][1]; o[2] = st[m][2];                  \
        } else {                                                                \
            outB[(size_t)(K) * NPc + p] = bb[m];                                \
        }                                                                       \
    }

    PH2(0, 0, 0, 8)
    PH2(1, 0, 1, 7)
    PH2(2, 1, 0, 6)
    PH2(3, 1, 1, 5)
    PH2(4, 2, 0, 4)
    PH2(5, 2, 1, 3)
#undef PH2

    // ---- epilogue: remaining biases (slots 0,1; identical on both lanes) ----
    LC += -0.5f * (LOG_2PI + bb[0] * bb[0]);
    LC += -0.5f * (LOG_2PI + bb[1] * bb[1]);
    if (q == 0) outL[p] = LC;
}

extern "C" void kernel_launch(void* const* d_in, const int* in_sizes, int n_in,
                              void* d_out, int out_size, void* d_ws, size_t ws_size,
                              hipStream_t stream) {
    const float* cur = (const float*)d_in[0];
    const float* nxt = (const float*)d_in[1];
    const float* bia = (const float*)d_in[2];
    float* out = (float*)d_out;

    // 2 threads per point: 256-thread blocks cover 128 points each.
    dim3 grid((NPc * 2) / 256), block(256);
    gaussmerge_kernel<<<grid, block, 0, stream>>>(cur, nxt, bia, out);
}